// Round 3
// 99321.045 us; speedup vs baseline: 1.4931x; 1.4931x over previous
//
#include <hip/hip_runtime.h>
#include <stdint.h>

#define H2 2048
#define TT 2048
#define NUNIT 2048
#define NSLOT (TT + 1)
#define GATES 8192
#define KB 64

typedef _Float16 half2v __attribute__((ext_vector_type(2)));

__device__ __forceinline__ float sigf(float x) { return 1.0f / (1.0f + __expf(-x)); }
__device__ __forceinline__ float tanhf_fast(float x) { return 1.0f - 2.0f / (__expf(2.0f * x) + 1.0f); }

// pack two floats to f16 pair with round-to-nearest (NOT pkrtz/RTZ)
__device__ __forceinline__ unsigned pk_rtn(float a, float b) {
  half2v h;
  h.x = (_Float16)a;
  h.y = (_Float16)b;
  return __builtin_bit_cast(unsigned, h);
}

// slots: u32 slots[2049][2048] (reused across layers); value = (tag<<16)|f16(h),
// tag = (layer<<13)|ti, ti = t+1 in 1..2048. Zeroed at launch start -> tag 0 never matches.
// h32: f32 h[t][u] for the current layer (plain stores; consumed by next kernel = stream-ordered).

// ---------- layer-0 input projection ----------
__global__ void __launch_bounds__(256) xw0_kernel(
    const float* __restrict__ event, const float* __restrict__ w0,
    const float* __restrict__ bi, const float* __restrict__ bh,
    float* __restrict__ xw)
{
  const int row = blockIdx.x;              // 0..8191
  const float wv = w0[row];
  const float b  = bi[row] + bh[row];
  float* o = xw + (size_t)row * TT;
#pragma unroll
  for (int i = 0; i < 8; ++i) {
    const int t = (i << 8) + threadIdx.x;
    o[t] = fmaf(event[t], wv, b);
  }
}

// ---------- input projection GEMM, full f32 ----------
// xw[row][t] = sum_k W[row][k] * h32[t][k] + bi[row] + bh[row]
// tile: 64 rows x 128 t, k-block 64; grid = 128 row-tiles * 16 t-tiles = 2048 blocks.
__global__ void __launch_bounds__(256) xw_gemm(
    const float* __restrict__ h32,         // [2048][2048]
    const float* __restrict__ W,           // w_ih[l-1]: [8192][2048]
    const float* __restrict__ bi, const float* __restrict__ bh,
    float* __restrict__ xw)
{
  __shared__ float lds_h[128][KB + 1];     // 33.3 KB
  __shared__ float lds_w[64][KB + 1];      // 16.6 KB
  const int tid = threadIdx.x;
  const int t0 = (blockIdx.x & 15) << 7;   // t-tile * 128
  const int r0 = (blockIdx.x >> 4) << 6;   // row-tile * 64
  const int tx = tid & 15, ty = tid >> 4;

  float acc[4][8];
#pragma unroll
  for (int m = 0; m < 4; ++m)
#pragma unroll
    for (int j = 0; j < 8; ++j) acc[m][j] = 0.f;

  for (int k0 = 0; k0 < H2; k0 += KB) {
    __syncthreads();
    // stage h: 128t x 64k
#pragma unroll
    for (int i = 0; i < 32; ++i) {
      const int idx = (i << 8) + tid;
      const int tt = idx >> 6, kk = idx & 63;
      lds_h[tt][kk] = h32[(size_t)(t0 + tt) * NUNIT + (k0 + kk)];
    }
    // stage W: 64r x 64k
#pragma unroll
    for (int i = 0; i < 16; ++i) {
      const int idx = (i << 8) + tid;
      const int rr = idx >> 6, kk = idx & 63;
      lds_w[rr][kk] = W[(size_t)(r0 + rr) * H2 + (k0 + kk)];
    }
    __syncthreads();
#pragma unroll 4
    for (int kp = 0; kp < KB; ++kp) {
      float wv[4], hv[8];
#pragma unroll
      for (int m = 0; m < 4; ++m) wv[m] = lds_w[ty + (m << 4)][kp];
#pragma unroll
      for (int j = 0; j < 8; ++j) hv[j] = lds_h[tx + (j << 4)][kp];
#pragma unroll
      for (int m = 0; m < 4; ++m)
#pragma unroll
        for (int j = 0; j < 8; ++j)
          acc[m][j] = fmaf(wv[m], hv[j], acc[m][j]);
    }
  }
  // epilogue: + bias, store f32 xw[row][t]
#pragma unroll
  for (int m = 0; m < 4; ++m) {
    const int row = r0 + ty + (m << 4);
    const float b = bi[row] + bh[row];
    float* o = xw + (size_t)row * TT + t0 + tx;
#pragma unroll
    for (int j = 0; j < 8; ++j) o[j << 4] = acc[m][j] + b;
  }
}

// ---------- recurrent scan for one layer: w_hh register-resident (f16 RTN), 1 wave = 1 h-unit ----------
__global__ void __launch_bounds__(256, 2) rnn_scan_layer(
    const float* __restrict__ whh_l,   // w_hh + l*8192*2048
    const float* __restrict__ xw,      // [8192][2048] f32
    unsigned* slots,                   // [2049][2048] tagged f16
    float* __restrict__ h32,           // [2048][2048] f32 out
    int l)
{
  const int wave = threadIdx.x >> 6;
  const int lane = threadIdx.x & 63;
  const int u = (blockIdx.x << 2) | wave;   // h-unit 0..2047

  unsigned wreg[64];
#pragma unroll
  for (int m = 0; m < 4; ++m) {
    const float* p = whh_l + (size_t)((m << 11) + u) * H2 + (lane << 1);
#pragma unroll
    for (int i = 0; i < 16; ++i) {
      const float2 f = *(const float2*)(p + (i << 7));
      wreg[(m << 4) + i] = pk_rtn(f.x, f.y);
    }
  }
  const float* xwp = xw + (size_t)u * TT;
  const unsigned ltag = (unsigned)l << 13;
  float c = 0.f;

  for (int t = 0; t < TT; ++t) {
    // xw loads issued before the spin; latency hides under it
    const float x0 = xwp[t];
    const float x1 = xwp[(size_t)1 * H2 * TT + t];
    const float x2 = xwp[(size_t)2 * H2 * TT + t];
    const float x3 = xwp[(size_t)3 * H2 * TT + t];

    unsigned h2[16];
    if (t == 0) {
#pragma unroll
      for (int i = 0; i < 16; ++i) h2[i] = 0u;
    } else {
      const unsigned long long* sp = (const unsigned long long*)(slots + (size_t)t * NUNIT);
      const unsigned tag = ltag | (unsigned)t;
      const unsigned long long pat =
          ((unsigned long long)tag << 16) | ((unsigned long long)tag << 48);
      unsigned long long v[16];
#pragma unroll
      for (int i = 0; i < 16; ++i)
        v[i] = __hip_atomic_load(&sp[lane + (i << 6)], __ATOMIC_RELAXED, __HIP_MEMORY_SCOPE_AGENT);
      bool bad = true;
      while (bad) {
        bad = false;
#pragma unroll
        for (int i = 0; i < 16; ++i) {
          if ((v[i] & 0xFFFF0000FFFF0000ull) != pat) {
            v[i] = __hip_atomic_load(&sp[lane + (i << 6)], __ATOMIC_RELAXED, __HIP_MEMORY_SCOPE_AGENT);
            bad = true;
          }
        }
      }
#pragma unroll
      for (int i = 0; i < 16; ++i)
        h2[i] = ((unsigned)v[i] & 0xffffu) | (((unsigned)(v[i] >> 32) & 0xffffu) << 16);
    }

    float a0 = 0.f, a1 = 0.f, a2 = 0.f, a3 = 0.f;
#pragma unroll
    for (int i = 0; i < 16; ++i) {
      const half2v hv = __builtin_bit_cast(half2v, h2[i]);
      a0 = __builtin_amdgcn_fdot2(__builtin_bit_cast(half2v, wreg[i]),      hv, a0, false);
      a1 = __builtin_amdgcn_fdot2(__builtin_bit_cast(half2v, wreg[16 + i]), hv, a1, false);
      a2 = __builtin_amdgcn_fdot2(__builtin_bit_cast(half2v, wreg[32 + i]), hv, a2, false);
      a3 = __builtin_amdgcn_fdot2(__builtin_bit_cast(half2v, wreg[48 + i]), hv, a3, false);
    }
#pragma unroll
    for (int s = 1; s < 64; s <<= 1) {
      a0 += __shfl_xor(a0, s, 64);
      a1 += __shfl_xor(a1, s, 64);
      a2 += __shfl_xor(a2, s, 64);
      a3 += __shfl_xor(a3, s, 64);
    }

    const float gi = a0 + x0, gf = a1 + x1, gg = a2 + x2, go = a3 + x3;
    c = sigf(gf) * c + sigf(gi) * tanhf_fast(gg);
    const float h = sigf(go) * tanhf_fast(c);

    if (lane == 0) {
      const unsigned hb = (unsigned)__builtin_bit_cast(unsigned short, (_Float16)h);
      const unsigned stag = ltag | (unsigned)(t + 1);
      __hip_atomic_store(&slots[(size_t)(t + 1) * NUNIT + u],
                         (stag << 16) | hb,
                         __ATOMIC_RELAXED, __HIP_MEMORY_SCOPE_AGENT);
      h32[(size_t)t * NUNIT + u] = h;
    }
  }
}

__global__ void rnn_tail(const float* __restrict__ h32,
                         const float* __restrict__ w_out,
                         const float* __restrict__ b_out,
                         float* __restrict__ out)
{
  __shared__ float red0[4], red1[4];
  const int tid = threadIdx.x;
  float s0 = 0.f, s1 = 0.f;
  const float* hp = h32 + (size_t)(TT - 1) * NUNIT;   // h^3(2047), f32
  for (int q = tid; q < NUNIT; q += 256) {
    const float f = hp[q];
    s0 = fmaf(f, w_out[q], s0);
    s1 = fmaf(f, w_out[H2 + q], s1);
  }
#pragma unroll
  for (int s = 1; s < 64; s <<= 1) { s0 += __shfl_xor(s0, s, 64); s1 += __shfl_xor(s1, s, 64); }
  if ((tid & 63) == 0) { red0[tid >> 6] = s0; red1[tid >> 6] = s1; }
  __syncthreads();
  if (tid == 0) {
    const float l0 = red0[0] + red0[1] + red0[2] + red0[3] + b_out[0];
    const float l1 = red1[0] + red1[1] + red1[2] + red1[3] + b_out[1];
    const float mx = fmaxf(l0, l1);
    const float lse = mx + logf(__expf(l0 - mx) + __expf(l1 - mx));
    out[0] = l0 - lse;
    out[1] = l1 - lse;
  }
}

extern "C" void kernel_launch(void* const* d_in, const int* in_sizes, int n_in,
                              void* d_out, int out_size, void* d_ws, size_t ws_size,
                              hipStream_t stream)
{
  const float* event = (const float*)d_in[0];
  const float* w_ih0 = (const float*)d_in[1];
  const float* w_ih  = (const float*)d_in[2];
  const float* w_hh  = (const float*)d_in[3];
  const float* b_ih  = (const float*)d_in[4];
  const float* b_hh  = (const float*)d_in[5];
  const float* w_out = (const float*)d_in[6];
  const float* b_out = (const float*)d_in[7];

  unsigned* slots = (unsigned*)d_ws;                             // 2049*2048*4   = 16.8 MB
  float* xw  = (float*)(slots + (size_t)NSLOT * NUNIT);          // 8192*2048*4   = 67.1 MB
  float* h32 = xw + (size_t)GATES * TT;                          // 2048*2048*4   = 16.8 MB

  (void)hipMemsetAsync(slots, 0, (size_t)NSLOT * NUNIT * sizeof(unsigned), stream);

  hipLaunchKernelGGL(xw0_kernel, dim3(GATES), dim3(256), 0, stream,
                     event, w_ih0, b_ih, b_hh, xw);

  int lv[4] = {0, 1, 2, 3};
  for (int l = 0; l < 4; ++l) {
    if (l > 0) {
      hipLaunchKernelGGL(xw_gemm, dim3(2048), dim3(256), 0, stream,
                         (const float*)h32,
                         w_ih + (size_t)(l - 1) * GATES * H2,
                         b_ih + (size_t)l * GATES, b_hh + (size_t)l * GATES, xw);
    }
    const float* whh_l = w_hh + (size_t)l * GATES * H2;
    const float* xwc   = xw;
    unsigned* slc      = slots;
    float* h32c        = h32;
    void* args[] = {(void*)&whh_l, (void*)&xwc, (void*)&slc, (void*)&h32c, (void*)&lv[l]};
    (void)hipLaunchCooperativeKernel((void*)rnn_scan_layer, dim3(512), dim3(256), args, 0, stream);
  }

  hipLaunchKernelGGL(rnn_tail, dim3(1), dim3(256), 0, stream,
                     (const float*)h32, w_out, b_out, (float*)d_out);
}